// Round 3
// baseline (244.541 us; speedup 1.0000x reference)
//
#include <hip/hip_runtime.h>
#include <stdint.h>

// R7: NCONF=8192, NT=64, NX=64
// out0[i,t,j] = sum_y phi[i,t,y] * W[(y+T0)&63, (j+T0)&63] + b[(j+T0)&63]
// out1[i]     = 64 * log|det W|
//
// Theory R7: R4/R5/R6 (three disjoint transaction structures) all = 82-85us
// -> not transaction-shape-bound, not byte-bound. Per-CU: 1MB in 85us =
// 12GB/s/CU vs fill's 26GB/s/CU => read-concurrency x duty-cycle bound:
// loads in flight only ~50% of wave lifetime, ~5 waves/CU resident.
// Fix: per-wave 4-config pipeline where next cfg's 16 dwordx4 loads are
// ALWAYS outstanding during current cfg's compute. R5's version of this was
// silently serialized by the compiler (VGPR stayed 100); here load issue
// points are pinned with asm memory fences (global loads cannot cross a
// "memory"-clobber asm). f16 staging (8KB/cfg, dbuf 16KB/wave, 32KB/block,
// 2 waves/block) -> 4 blocks/CU = 8 waves/CU. LU runs on block 1 wave 0
// before its GEMM share (hides under the other waves' BW-bound time; no
// serialized prep, no tail block).

typedef _Float16 half8v __attribute__((ext_vector_type(8)));
typedef _Float16 half4v __attribute__((ext_vector_type(4)));
typedef float float4v __attribute__((ext_vector_type(4)));

__device__ __forceinline__ float rdlane_f(float v, int l) {
  return __int_as_float(__builtin_amdgcn_readlane(__float_as_int(v), l));
}

// WT2[s][j][y] = (f16) W[(y+s)&63][(j+s)&63]   (y contiguous)
__global__ __launch_bounds__(256) void wt2_prep(const float* __restrict__ W,
                                                _Float16* __restrict__ wt2) {
  const int s = blockIdx.x;
  const int tid = threadIdx.x;
#pragma unroll
  for (int it = 0; it < 16; ++it) {
    int flat = it * 256 + tid;
    int j = flat >> 6, y = flat & 63;
    wt2[(size_t)s * 4096 + flat] =
        (_Float16)W[((y + s) & 63) * 64 + ((j + s) & 63)];
  }
}

__global__ __launch_bounds__(128, 2) void equiv_main(
    const float* __restrict__ phi, const float* __restrict__ W,
    const float* __restrict__ b, const _Float16* __restrict__ wt2,
    float* __restrict__ out) {
  // 2 waves x 2 buffers x 8KB f16 staging (wave-private, no __syncthreads)
  __shared__ __align__(16) _Float16 smem[2][2][4096];
  const int lane = threadIdx.x & 63;
  const int wave = threadIdx.x >> 6;
  const int m = lane & 15;  // MFMA row/col within 16-tile
  const int q = lane >> 4;  // quad

  if (blockIdx.x == 1 && wave == 0) {
    // ---- register LU, no pivoting (W = I + 0.1*N(0,1)): lane t owns row t;
    // shift-down keeps pivot col at r[0]; uniform-k readlane broadcast.
    // Runs BEFORE this wave's GEMM share; hides under other waves' BW time.
    const int t = lane;
    float r[64];
#pragma unroll
    for (int i = 0; i < 64; ++i) r[i] = W[t * 64 + i];
    float ldsum = 0.f;
#pragma unroll 1
    for (int k = 0; k < 64; ++k) {
      float v0 = r[0];
      float piv = rdlane_f(v0, k);
      ldsum += logf(fabsf(piv));
      float mf = v0 / piv;
#pragma unroll
      for (int i = 1; i < 64; ++i) {
        float pe = rdlane_f(r[i], k);
        r[i - 1] = r[i] - mf * pe;
      }
      r[63] = 0.f;
    }
    float ld = 64.0f * ldsum;  // NT * logabsdet
    float* outLD = out + (size_t)8192 * 4096;
#pragma unroll
    for (int it = 0; it < 128; ++it) outLD[it * 64 + t] = ld;
    // fall through to GEMM
  }

  const int cfg0 = ((int)blockIdx.x * 2 + wave) * 4;

  float4v frA[16], frB[16];

  // issue 16 contiguous dwordx4 loads for cfg (cfg0+k): 1KB per instr
  auto issue = [&](int k, float4v(&fr)[16]) {
    const float* ph = phi + (size_t)(cfg0 + k) * 4096;
#pragma unroll
    for (int i = 0; i < 16; ++i)
      fr[i] = *(const float4v*)&ph[i * 256 + lane * 4];
  };

  auto body = [&](int k, float4v(&fr)[16], float4v(&frn)[16]) {
    _Float16* buf = smem[wave][k & 1];
    // ---- T0 argmin from in-register f32 (exact bit semantics) ----
    // fr[i] holds row i*4+q, cols (lane&15)*4..+3 -> cols 0,1 live at m==0
    unsigned long long k0 = ~0ull, k1 = ~0ull;
    if (m == 0) {
#pragma unroll
      for (int i = 0; i < 16; ++i) {
        unsigned long long tt = (unsigned long long)(i * 4 + q);
        unsigned long long c0 =
            (((unsigned long long)__float_as_uint(fabsf(fr[i].x))) << 6) | tt;
        unsigned long long c1 =
            (((unsigned long long)__float_as_uint(fabsf(fr[i].y))) << 6) | tt;
        k0 = c0 < k0 ? c0 : k0;
        k1 = c1 < k1 ? c1 : k1;
      }
    }
#pragma unroll
    for (int s = 1; s < 64; s <<= 1) {
      unsigned long long o0 = __shfl_xor(k0, s);
      unsigned long long o1 = __shfl_xor(k1, s);
      k0 = o0 < k0 ? o0 : k0;
      k1 = o1 < k1 ? o1 : k1;
    }
    const int t0i = (int)(k0 & 63ull), t1i = (int)(k1 & 63ull);
    const int T0 = (t0i > t1i) ? t1i : t0i;

    // ---- issue B fragments + bias early (L2 latency hides under staging) --
    const _Float16* wt = wt2 + (size_t)T0 * 4096;
    half8v Bf[2][4];
#pragma unroll
    for (int ks = 0; ks < 2; ++ks)
#pragma unroll
      for (int nt = 0; nt < 4; ++nt)
        Bf[ks][nt] = *(const half8v*)&wt[(nt * 16 + m) * 64 + ks * 32 + q * 8];
    float bias[4];
#pragma unroll
    for (int nt = 0; nt < 4; ++nt) bias[nt] = b[(nt * 16 + m + T0) & 63];
    asm volatile("" ::: "memory");  // pin B issue above staging

    // ---- stage fr -> f16 LDS, 16B-chunk XOR swizzle (chunk ^= row&7) ----
#pragma unroll
    for (int i = 0; i < 16; ++i) {
      int row = i * 4 + q;
      half4v h;
      h[0] = (_Float16)fr[i][0];
      h[1] = (_Float16)fr[i][1];
      h[2] = (_Float16)fr[i][2];
      h[3] = (_Float16)fr[i][3];
      // f16 elems: row*64 + chunk'*8 + (m&1)*4, chunk' = (m>>1) ^ (row&7)
      *(half4v*)&buf[row * 64 + ((((m >> 1) ^ (row & 7)) << 3) | ((m & 1) << 2))] = h;
    }

    // ---- prefetch next cfg NOW; fences forbid the compiler sinking it ----
    if (k < 3) issue(k + 1, frn);
    asm volatile("" ::: "memory");

    // ---- A fragments from staged LDS (2-way max on swizzled reads) ----
    half8v Af[4][2];
#pragma unroll
    for (int mt = 0; mt < 4; ++mt)
#pragma unroll
      for (int ks = 0; ks < 2; ++ks) {
        int row = mt * 16 + m;
        Af[mt][ks] =
            *(const half8v*)&buf[row * 64 + (((ks * 4 + q) ^ (row & 7)) << 3)];
      }

    // ---- 32 MFMAs ----
    float4v acc[4][4];
#pragma unroll
    for (int mt = 0; mt < 4; ++mt)
#pragma unroll
      for (int nt = 0; nt < 4; ++nt) acc[mt][nt] = (float4v)(0.f);
#pragma unroll
    for (int ks = 0; ks < 2; ++ks)
#pragma unroll
      for (int mt = 0; mt < 4; ++mt)
#pragma unroll
        for (int nt = 0; nt < 4; ++nt)
          acc[mt][nt] = __builtin_amdgcn_mfma_f32_16x16x32_f16(
              Af[mt][ks], Bf[ks][nt], acc[mt][nt], 0, 0, 0);

    // ---- epilogue: 2 stripes (32 rows f32) through the dead staging buf ----
    // acc[mt][nt][r] = out[row=mt*16+q*4+r][col=nt*16+m]; dword swizzle
    // col' = col ^ ((row&12)<<1) -> 2-way max both sides; b128-safe.
    float* fsm = (float*)buf;  // 8KB = 32 rows x 64 f32
    float* op = out + (size_t)(cfg0 + k) * 4096;
#pragma unroll
    for (int s = 0; s < 2; ++s) {
#pragma unroll
      for (int mh = 0; mh < 2; ++mh) {
        int mt = s * 2 + mh;
#pragma unroll
        for (int nt = 0; nt < 4; ++nt)
#pragma unroll
          for (int r2 = 0; r2 < 4; ++r2) {
            int lrow = mh * 16 + q * 4 + r2;
            fsm[lrow * 64 + ((nt * 16 + m) ^ ((lrow & 12) << 1))] =
                acc[mt][nt][r2] + bias[nt];
          }
      }
#pragma unroll
      for (int j = 0; j < 8; ++j) {
        int flat = j * 256 + lane * 4;
        int lrow = flat >> 6, colg = flat & 63;
        float4v v = *(const float4v*)&fsm[lrow * 64 + (colg ^ ((lrow & 12) << 1))];
        __builtin_nontemporal_store(v, (float4v*)&op[s * 2048 + flat]);
      }
    }
  };

  issue(0, frA);
  asm volatile("" ::: "memory");
  body(0, frA, frB);
  body(1, frB, frA);
  body(2, frA, frB);
  body(3, frB, frA);
}

extern "C" void kernel_launch(void* const* d_in, const int* in_sizes, int n_in,
                              void* d_out, int out_size, void* d_ws,
                              size_t ws_size, hipStream_t stream) {
  const float* phi = (const float*)d_in[0];
  const float* W = (const float*)d_in[1];
  const float* b = (const float*)d_in[2];
  float* out = (float*)d_out;
  _Float16* wt2 = (_Float16*)d_ws;  // 64 shifts x 64x64 f16 = 512 KB

  wt2_prep<<<dim3(64), dim3(256), 0, stream>>>(W, wt2);
  equiv_main<<<dim3(1024), dim3(128), 0, stream>>>(phi, W, b, wt2, out);
}